// Round 7
// baseline (615.596 us; speedup 1.0000x reference)
//
#include <hip/hip_runtime.h>

typedef __bf16 bf16;
typedef __bf16 bf16x8 __attribute__((ext_vector_type(8)));
typedef __bf16 bf16x4 __attribute__((ext_vector_type(4)));
typedef float f32x4 __attribute__((ext_vector_type(4)));

#define MFMA16(a, b, c) __builtin_amdgcn_mfma_f32_16x16x32_bf16(a, b, c, 0, 0, 0)

// Problem constants
#define Bq 2
#define Sq 2048
#define Eq 2048
#define Hq 16
#define Dq 128
#define N3E 6144

#define GLOAD_LDS16(gp, lp) \
  __builtin_amdgcn_global_load_lds( \
      (const __attribute__((address_space(1))) void*)(gp), \
      (__attribute__((address_space(3))) void*)(lp), 16, 0, 0)

__device__ __forceinline__ bf16 f2bf(float f) {
  unsigned u = __builtin_bit_cast(unsigned, f);
  u += 0x7FFFu + ((u >> 16) & 1u);
  unsigned short h = (unsigned short)(u >> 16);
  return __builtin_bit_cast(bf16, h);
}
__device__ __forceinline__ float bf2f(bf16 b) {
  unsigned short h = __builtin_bit_cast(unsigned short, b);
  return __builtin_bit_cast(float, (unsigned)h << 16);
}

// ---------------------------------------------------------------------------
// Kernel 0a: x fp32 -> xb bf16 (elementwise, 8 elems/thread)
// ---------------------------------------------------------------------------
__global__ __launch_bounds__(256) void convert_x(const float* __restrict__ x,
                                                 bf16* __restrict__ xb) {
  const size_t i = ((size_t)blockIdx.x * 256 + threadIdx.x) * 8;
  float4 a = *(const float4*)(x + i);
  float4 b = *(const float4*)(x + i + 4);
  bf16x8 o;
  o[0] = f2bf(a.x); o[1] = f2bf(a.y); o[2] = f2bf(a.z); o[3] = f2bf(a.w);
  o[4] = f2bf(b.x); o[5] = f2bf(b.y); o[6] = f2bf(b.z); o[7] = f2bf(b.w);
  *(bf16x8*)(xb + i) = o;
}

// ---------------------------------------------------------------------------
// Kernel 0b: W fp32 [k][n] -> wt bf16 [n][k] (64x64 LDS tile transpose)
// ---------------------------------------------------------------------------
__global__ __launch_bounds__(256) void convert_wt(const float* __restrict__ w,
                                                  bf16* __restrict__ wt) {
  __shared__ __align__(16) bf16 T[64][72];
  const int tid = threadIdx.x;
  const int kb = blockIdx.x & 31;  // 2048/64
  const int nb = blockIdx.x >> 5;  // 6144/64
  const int k0 = kb * 64, n0 = nb * 64;
  {
    const int kr = tid >> 4, nc = (tid & 15) * 4;
#pragma unroll
    for (int p = 0; p < 4; ++p) {
      const int k = kr + p * 16;
      float4 v = *(const float4*)(w + (size_t)(k0 + k) * N3E + n0 + nc);
      T[nc + 0][k] = f2bf(v.x);
      T[nc + 1][k] = f2bf(v.y);
      T[nc + 2][k] = f2bf(v.z);
      T[nc + 3][k] = f2bf(v.w);
    }
  }
  __syncthreads();
#pragma unroll
  for (int q = 0; q < 2; ++q) {
    const int id = q * 256 + tid;
    const int n = id >> 3, ch = id & 7;
    bf16x8 v = *(const bf16x8*)&T[n][ch * 8];
    *(bf16x8*)(wt + (size_t)(n0 + n) * Eq + k0 + ch * 8) = v;
  }
}

// ---------------------------------------------------------------------------
// Kernel 1: qkv = xb @ wt^T, m97-style K-loop + fused-RoPE epilogue.
// Grid = 768 blocks, each does TWO n-adjacent 128x128 tiles (same m0):
// uniform work -> no residency tail; A-slab L2-hot for the second tile.
// ---------------------------------------------------------------------------
__global__ __launch_bounds__(256) void gemm_qkv(
    const bf16* __restrict__ xb, const bf16* __restrict__ wt,
    bf16* __restrict__ qws, bf16* __restrict__ kws, bf16* __restrict__ vtws) {
  __shared__ __align__(16) bf16 Sm[128 * 136];  // 34 KB pool
  bf16* Ald = Sm;          // staging A: 8192 elems (16 KB)
  bf16* Bld = Sm + 8192;   // staging B: 8192 elems (16 KB)

  const int tid = threadIdx.x;
  const int lane = tid & 63, wave = tid >> 6;
  const int q4 = lane >> 4, c = lane & 15;
  const int p = blockIdx.x;
  const int m0 = (p / 24) * 128;
  const int npair = (p % 24) * 2;
  const int wm = (wave >> 1) * 64, wn = (wave & 1) * 64;

  for (int nt = 0; nt < 2; ++nt) {
    const int n0 = (npair + nt) * 128;

    f32x4 acc[4][4];
#pragma unroll
    for (int i = 0; i < 4; ++i)
#pragma unroll
      for (int j = 0; j < 4; ++j) acc[i][j] = {0.f, 0.f, 0.f, 0.f};

    for (int k0 = 0; k0 < Eq; k0 += 64) {
#pragma unroll
      for (int it = 0; it < 4; ++it) {
        const int slot = it * 256 + tid;
        const int chunk = slot >> 7, row = slot & 127;
        const bf16* gp = xb + (size_t)(m0 + row) * Eq + k0 + chunk * 8;
        GLOAD_LDS16(gp, Ald + slot * 8);
      }
#pragma unroll
      for (int it = 0; it < 4; ++it) {
        const int slot = it * 256 + tid;
        const int chunk = slot >> 7, row = slot & 127;
        const bf16* gp = wt + (size_t)(n0 + row) * Eq + k0 + chunk * 8;
        GLOAD_LDS16(gp, Bld + slot * 8);
      }
      __syncthreads();
#pragma unroll
      for (int kk = 0; kk < 64; kk += 32) {
        const int chunk = (kk >> 3) + q4;
        bf16x8 af[4], bfr[4];
#pragma unroll
        for (int i = 0; i < 4; ++i)
          af[i] = *(const bf16x8*)&Ald[(chunk * 128 + wm + i * 16 + c) * 8];
#pragma unroll
        for (int j = 0; j < 4; ++j)
          bfr[j] = *(const bf16x8*)&Bld[(chunk * 128 + wn + j * 16 + c) * 8];
#pragma unroll
        for (int i = 0; i < 4; ++i)
#pragma unroll
          for (int j = 0; j < 4; ++j)
            acc[i][j] = MFMA16(af[i], bfr[j], acc[i][j]);
      }
      __syncthreads();
    }

    // ---- epilogue via LDS transpose ----
    const int t = n0 >> 11;            // 0=q, 1=k, 2=v
    const int b = m0 >> 11;
    const int s0 = m0 & 2047;
    const int h = (n0 & 2047) >> 7;

    if (t == 2) {
#pragma unroll
      for (int i = 0; i < 4; ++i)
#pragma unroll
        for (int j = 0; j < 4; ++j) {
          bf16x4 pv;
          pv[0] = f2bf(acc[i][j][0]); pv[1] = f2bf(acc[i][j][1]);
          pv[2] = f2bf(acc[i][j][2]); pv[3] = f2bf(acc[i][j][3]);
          *(bf16x4*)&Sm[(wn + j * 16 + c) * 136 + wm + i * 16 + q4 * 4] = pv;
        }
      __syncthreads();
      bf16* vbase = vtws + ((size_t)(b * Hq + h) * Dq) * Sq + s0;
#pragma unroll
      for (int pp = 0; pp < 8; ++pp) {
        const int d = pp * 16 + (tid >> 4), chunk = tid & 15;
        bf16x8 v = *(const bf16x8*)&Sm[d * 136 + chunk * 8];
        *(bf16x8*)&vbase[(size_t)d * Sq + chunk * 8] = v;
      }
    } else {
#pragma unroll
      for (int i = 0; i < 4; ++i)
#pragma unroll
        for (int j = 0; j < 4; ++j)
#pragma unroll
          for (int rr = 0; rr < 4; ++rr)
            Sm[(wm + i * 16 + q4 * 4 + rr) * 136 + wn + j * 16 + c] =
                f2bf(acc[i][j][rr]);
      __syncthreads();
      bf16* dst =
          ((t == 0) ? qws : kws) + ((size_t)(b * Hq + h) * Sq + s0) * Dq;
#pragma unroll
      for (int pp = 0; pp < 4; ++pp) {
        const int row = pp * 32 + (tid >> 3);
        const int dlow = (tid & 7) * 8;
        const int s = s0 + row;
        bf16x8 lo = *(const bf16x8*)&Sm[row * 136 + dlow];
        bf16x8 hi = *(const bf16x8*)&Sm[row * 136 + 64 + dlow];
        bf16x8 olo, ohi;
#pragma unroll
        for (int e = 0; e < 8; ++e) {
          const int d = dlow + e;
          const float freq = __expf(-(float)d * 0.14391157f);
          const float ang = (float)s * freq;
          float sv, cv;
          __sincosf(ang, &sv, &cv);
          const float x1 = bf2f(lo[e]), x2 = bf2f(hi[e]);
          olo[e] = f2bf(x1 * cv - x2 * sv);
          ohi[e] = f2bf(x2 * cv + x1 * sv);
        }
        *(bf16x8*)&dst[(size_t)row * Dq + dlow] = olo;
        *(bf16x8*)&dst[(size_t)row * Dq + 64 + dlow] = ohi;
      }
    }
    __syncthreads();  // Sm reads done before next tile's staging overwrites
  }
}

// ---------------------------------------------------------------------------
// Kernel 3: flash attention (R5 version, reverted from R6 regression).
// Block = 128 q-rows: 4 waves x 32 q (two 16-col groups). Chunk = 64 keys,
// double-buffered DMA. S^T = K·Q^T -> per-lane scalar softmax (q=lane&15),
// P^T via per-wave LDS (no barrier), O^T = V^T·P^T.
// ---------------------------------------------------------------------------
__global__ __launch_bounds__(256, 2) void attn_kernel(
    const bf16* __restrict__ qws, const bf16* __restrict__ kws,
    const bf16* __restrict__ vtws, float* __restrict__ out) {
  __shared__ __align__(16) bf16 Kld[2][8192];
  __shared__ __align__(16) bf16 Vld[2][8192];
  __shared__ __align__(16) bf16 Plds[4][16][72];

  const int tid = threadIdx.x, lane = tid & 63, wave = tid >> 6;
  const int q4 = lane >> 4, c = lane & 15;
  const int qt = 15 - blockIdx.x;  // descending dispatch
  const int h = blockIdx.y, b = blockIdx.z;
  const size_t bh = (size_t)(b * Hq + h);
  const bf16* qbase = qws + bh * Sq * Dq;
  const bf16* kbase = kws + bh * Sq * Dq;
  const bf16* vbase = vtws + bh * Dq * Sq;
  const int q0 = qt * 128 + wave * 32;
  const float kSc = 0.08838834764831845f * 1.4426950408889634f;

  bf16x8 qf[2][4];
#pragma unroll
  for (int g = 0; g < 2; ++g)
#pragma unroll
    for (int ks = 0; ks < 4; ++ks)
      qf[g][ks] = *(const bf16x8*)
          &qbase[(size_t)(q0 + g * 16 + c) * Dq + ks * 32 + q4 * 8];

  f32x4 Ot[2][8];
  float m_i[2], l_i[2];
#pragma unroll
  for (int g = 0; g < 2; ++g) {
#pragma unroll
    for (int dj = 0; dj < 8; ++dj) Ot[g][dj] = {0.f, 0.f, 0.f, 0.f};
    m_i[g] = -1e30f; l_i[g] = 0.f;
  }

  const int nchunks = 2 * qt + 2;

#pragma unroll
  for (int it = 0; it < 4; ++it) {
    const int slot = it * 256 + tid;
    GLOAD_LDS16(kbase + (size_t)(slot & 63) * Dq + (slot >> 6) * 8,
                &Kld[0][slot * 8]);
    GLOAD_LDS16(vbase + (size_t)(slot & 127) * Sq + (slot >> 7) * 8,
                &Vld[0][slot * 8]);
  }
  __syncthreads();

  for (int kb = 0; kb < nchunks; ++kb) {
    const int buf = kb & 1;
    if (kb + 1 < nchunks) {
      const int nb = buf ^ 1;
      const int koff = (kb + 1) * 64;
#pragma unroll
      for (int it = 0; it < 4; ++it) {
        const int slot = it * 256 + tid;
        GLOAD_LDS16(kbase + (size_t)(koff + (slot & 63)) * Dq + (slot >> 6) * 8,
                    &Kld[nb][slot * 8]);
        GLOAD_LDS16(vbase + (size_t)(slot & 127) * Sq + koff + (slot >> 7) * 8,
                    &Vld[nb][slot * 8]);
      }
    }
    const bool masked = (kb >= 2 * qt);
#pragma unroll
    for (int g = 0; g < 2; ++g) {
      const int qg = q0 + g * 16 + c;
      f32x4 st[4];
#pragma unroll
      for (int j8 = 0; j8 < 4; ++j8) st[j8] = {0.f, 0.f, 0.f, 0.f};
#pragma unroll
      for (int ks = 0; ks < 4; ++ks) {
        const bf16x8 qv = qf[g][ks];
#pragma unroll
        for (int j8 = 0; j8 < 4; ++j8) {
          const bf16x8 kv = *(const bf16x8*)
              &Kld[buf][((ks * 4 + q4) * 64 + j8 * 16 + c) * 8];
          st[j8] = MFMA16(kv, qv, st[j8]);
        }
      }
      if (masked) {
        const int kb64 = kb * 64 + q4 * 4;
#pragma unroll
        for (int j8 = 0; j8 < 4; ++j8)
#pragma unroll
          for (int rr = 0; rr < 4; ++rr)
            if (kb64 + j8 * 16 + rr > qg) st[j8][rr] = -1e30f;
      }
      float mloc = -1e30f;
#pragma unroll
      for (int j8 = 0; j8 < 4; ++j8)
#pragma unroll
        for (int rr = 0; rr < 4; ++rr) mloc = fmaxf(mloc, st[j8][rr]);
      mloc = fmaxf(mloc, __shfl_xor(mloc, 16, 64));
      mloc = fmaxf(mloc, __shfl_xor(mloc, 32, 64));
      const float mn = fmaxf(m_i[g], mloc);
      const float alpha = exp2f((m_i[g] - mn) * kSc);
      m_i[g] = mn;
      float ssum = 0.f;
#pragma unroll
      for (int j8 = 0; j8 < 4; ++j8)
#pragma unroll
        for (int rr = 0; rr < 4; ++rr) {
          const float p = exp2f((st[j8][rr] - mn) * kSc);
          st[j8][rr] = p;
          ssum += p;
        }
      ssum += __shfl_xor(ssum, 16, 64);
      ssum += __shfl_xor(ssum, 32, 64);
      l_i[g] = l_i[g] * alpha + ssum;
#pragma unroll
      for (int dj = 0; dj < 8; ++dj) Ot[g][dj] *= alpha;
#pragma unroll
      for (int j8 = 0; j8 < 4; ++j8) {
        bf16x4 pk;
        pk[0] = f2bf(st[j8][0]); pk[1] = f2bf(st[j8][1]);
        pk[2] = f2bf(st[j8][2]); pk[3] = f2bf(st[j8][3]);
        *(bf16x4*)&Plds[wave][c][j8 * 16 + q4 * 4] = pk;
      }
#pragma unroll
      for (int ks = 0; ks < 2; ++ks) {
        const bf16x8 pv = *(const bf16x8*)&Plds[wave][c][ks * 32 + q4 * 8];
#pragma unroll
        for (int dj = 0; dj < 8; ++dj) {
          const bf16x8 vv = *(const bf16x8*)
              &Vld[buf][((ks * 4 + q4) * 128 + dj * 16 + c) * 8];
          Ot[g][dj] = MFMA16(vv, pv, Ot[g][dj]);
        }
      }
    }
    __syncthreads();
  }

#pragma unroll
  for (int g = 0; g < 2; ++g) {
    const float inv = 1.0f / l_i[g];
    float* orow = out + ((size_t)b * Sq + q0 + g * 16 + c) * Eq + h * Dq;
#pragma unroll
    for (int dj = 0; dj < 8; ++dj) {
      float4 o;
      o.x = Ot[g][dj][0] * inv; o.y = Ot[g][dj][1] * inv;
      o.z = Ot[g][dj][2] * inv; o.w = Ot[g][dj][3] * inv;
      *(float4*)&orow[dj * 16 + q4 * 4] = o;
    }
  }
}

// ---------------------------------------------------------------------------
extern "C" void kernel_launch(void* const* d_in, const int* in_sizes, int n_in,
                              void* d_out, int out_size, void* d_ws,
                              size_t ws_size, hipStream_t stream) {
  const float* x = (const float*)d_in[0];
  // d_in[1] = mask (causal tril) — implemented analytically, not read.
  const float* w = (const float*)d_in[2];
  float* out = (float*)d_out;

  const size_t nX = (size_t)Bq * Sq * Eq;         // 8,388,608
  const size_t nW = (size_t)Eq * N3E;             // 12,582,912
  const size_t perT = (size_t)Bq * Hq * Sq * Dq;  // 8,388,608

  bf16* xb = (bf16*)d_ws;
  bf16* wt = xb + nX;
  bf16* qws = wt + nW;
  bf16* kws = qws + perT;
  bf16* vtws = kws + perT;

  convert_x<<<nX / (256 * 8), 256, 0, stream>>>(x, xb);
  convert_wt<<<(Eq / 64) * (N3E / 64), 256, 0, stream>>>(w, wt);

  gemm_qkv<<<768, 256, 0, stream>>>(xb, wt, qws, kws, vtws);

  dim3 g3(Sq / 128, Hq, Bq);  // 16 x 16 x 2, qt descending
  attn_kernel<<<g3, 256, 0, stream>>>(qws, kws, vtws, out);
}

// Round 8
// 439.644 us; speedup vs baseline: 1.4002x; 1.4002x over previous
//
#include <hip/hip_runtime.h>

typedef __bf16 bf16;
typedef __bf16 bf16x8 __attribute__((ext_vector_type(8)));
typedef __bf16 bf16x4 __attribute__((ext_vector_type(4)));
typedef float f32x4 __attribute__((ext_vector_type(4)));

#define MFMA16(a, b, c) __builtin_amdgcn_mfma_f32_16x16x32_bf16(a, b, c, 0, 0, 0)

// Problem constants
#define Bq 2
#define Sq 2048
#define Eq 2048
#define Hq 16
#define Dq 128
#define N3E 6144

#define GLOAD_LDS16(gp, lp) \
  __builtin_amdgcn_global_load_lds( \
      (const __attribute__((address_space(1))) void*)(gp), \
      (__attribute__((address_space(3))) void*)(lp), 16, 0, 0)

__device__ __forceinline__ bf16 f2bf(float f) {
  unsigned u = __builtin_bit_cast(unsigned, f);
  u += 0x7FFFu + ((u >> 16) & 1u);
  unsigned short h = (unsigned short)(u >> 16);
  return __builtin_bit_cast(bf16, h);
}
__device__ __forceinline__ float bf2f(bf16 b) {
  unsigned short h = __builtin_bit_cast(unsigned short, b);
  return __builtin_bit_cast(float, (unsigned)h << 16);
}

// ---------------------------------------------------------------------------
// Kernel 0a: x fp32 -> xb bf16 (elementwise, 8 elems/thread)
// ---------------------------------------------------------------------------
__global__ __launch_bounds__(256) void convert_x(const float* __restrict__ x,
                                                 bf16* __restrict__ xb) {
  const size_t i = ((size_t)blockIdx.x * 256 + threadIdx.x) * 8;
  float4 a = *(const float4*)(x + i);
  float4 b = *(const float4*)(x + i + 4);
  bf16x8 o;
  o[0] = f2bf(a.x); o[1] = f2bf(a.y); o[2] = f2bf(a.z); o[3] = f2bf(a.w);
  o[4] = f2bf(b.x); o[5] = f2bf(b.y); o[6] = f2bf(b.z); o[7] = f2bf(b.w);
  *(bf16x8*)(xb + i) = o;
}

// ---------------------------------------------------------------------------
// Kernel 0b: W fp32 [k][n] -> wt bf16 [n][k] (64x64 LDS tile transpose)
// ---------------------------------------------------------------------------
__global__ __launch_bounds__(256) void convert_wt(const float* __restrict__ w,
                                                  bf16* __restrict__ wt) {
  __shared__ __align__(16) bf16 T[64][72];
  const int tid = threadIdx.x;
  const int kb = blockIdx.x & 31;  // 2048/64
  const int nb = blockIdx.x >> 5;  // 6144/64
  const int k0 = kb * 64, n0 = nb * 64;
  {
    const int kr = tid >> 4, nc = (tid & 15) * 4;
#pragma unroll
    for (int p = 0; p < 4; ++p) {
      const int k = kr + p * 16;
      float4 v = *(const float4*)(w + (size_t)(k0 + k) * N3E + n0 + nc);
      T[nc + 0][k] = f2bf(v.x);
      T[nc + 1][k] = f2bf(v.y);
      T[nc + 2][k] = f2bf(v.z);
      T[nc + 3][k] = f2bf(v.w);
    }
  }
  __syncthreads();
#pragma unroll
  for (int q = 0; q < 2; ++q) {
    const int id = q * 256 + tid;
    const int n = id >> 3, ch = id & 7;
    bf16x8 v = *(const bf16x8*)&T[n][ch * 8];
    *(bf16x8*)(wt + (size_t)(n0 + n) * Eq + k0 + ch * 8) = v;
  }
}

// ---------------------------------------------------------------------------
// Kernel 1: qkv = xb @ wt^T, m97-style K-loop + fused-RoPE epilogue.
// Exact R5 version (single 128x128 tile per block; R7's 2-tile loop blew
// VGPR 124->200 and regressed — reverted).
// ---------------------------------------------------------------------------
__global__ __launch_bounds__(256) void gemm_qkv(
    const bf16* __restrict__ xb, const bf16* __restrict__ wt,
    bf16* __restrict__ qws, bf16* __restrict__ kws, bf16* __restrict__ vtws) {
  __shared__ __align__(16) bf16 Sm[128 * 136];  // 34 KB pool
  bf16* Ald = Sm;          // staging A: 8192 elems (16 KB)
  bf16* Bld = Sm + 8192;   // staging B: 8192 elems (16 KB)

  const int tid = threadIdx.x;
  const int lane = tid & 63, wave = tid >> 6;
  const int q4 = lane >> 4, c = lane & 15;
  const int m0 = blockIdx.y * 128, n0 = blockIdx.x * 128;
  const int wm = (wave >> 1) * 64, wn = (wave & 1) * 64;

  f32x4 acc[4][4];
#pragma unroll
  for (int i = 0; i < 4; ++i)
#pragma unroll
    for (int j = 0; j < 4; ++j) acc[i][j] = {0.f, 0.f, 0.f, 0.f};

  for (int k0 = 0; k0 < Eq; k0 += 64) {
#pragma unroll
    for (int it = 0; it < 4; ++it) {
      const int slot = it * 256 + tid;
      const int chunk = slot >> 7, row = slot & 127;
      const bf16* gp = xb + (size_t)(m0 + row) * Eq + k0 + chunk * 8;
      GLOAD_LDS16(gp, Ald + slot * 8);
    }
#pragma unroll
    for (int it = 0; it < 4; ++it) {
      const int slot = it * 256 + tid;
      const int chunk = slot >> 7, row = slot & 127;
      const bf16* gp = wt + (size_t)(n0 + row) * Eq + k0 + chunk * 8;
      GLOAD_LDS16(gp, Bld + slot * 8);
    }
    __syncthreads();
#pragma unroll
    for (int kk = 0; kk < 64; kk += 32) {
      const int chunk = (kk >> 3) + q4;
      bf16x8 af[4], bfr[4];
#pragma unroll
      for (int i = 0; i < 4; ++i)
        af[i] = *(const bf16x8*)&Ald[(chunk * 128 + wm + i * 16 + c) * 8];
#pragma unroll
      for (int j = 0; j < 4; ++j)
        bfr[j] = *(const bf16x8*)&Bld[(chunk * 128 + wn + j * 16 + c) * 8];
#pragma unroll
      for (int i = 0; i < 4; ++i)
#pragma unroll
        for (int j = 0; j < 4; ++j)
          acc[i][j] = MFMA16(af[i], bfr[j], acc[i][j]);
    }
    __syncthreads();
  }

  // ---- epilogue via LDS transpose ----
  const int t = n0 >> 11;            // 0=q, 1=k, 2=v
  const int b = m0 >> 11;
  const int s0 = m0 & 2047;
  const int h = (n0 & 2047) >> 7;

  if (t == 2) {
#pragma unroll
    for (int i = 0; i < 4; ++i)
#pragma unroll
      for (int j = 0; j < 4; ++j) {
        bf16x4 pv;
        pv[0] = f2bf(acc[i][j][0]); pv[1] = f2bf(acc[i][j][1]);
        pv[2] = f2bf(acc[i][j][2]); pv[3] = f2bf(acc[i][j][3]);
        *(bf16x4*)&Sm[(wn + j * 16 + c) * 136 + wm + i * 16 + q4 * 4] = pv;
      }
    __syncthreads();
    bf16* vbase = vtws + ((size_t)(b * Hq + h) * Dq) * Sq + s0;
#pragma unroll
    for (int p = 0; p < 8; ++p) {
      const int d = p * 16 + (tid >> 4), chunk = tid & 15;
      bf16x8 v = *(const bf16x8*)&Sm[d * 136 + chunk * 8];
      *(bf16x8*)&vbase[(size_t)d * Sq + chunk * 8] = v;
    }
  } else {
#pragma unroll
    for (int i = 0; i < 4; ++i)
#pragma unroll
      for (int j = 0; j < 4; ++j)
#pragma unroll
        for (int rr = 0; rr < 4; ++rr)
          Sm[(wm + i * 16 + q4 * 4 + rr) * 136 + wn + j * 16 + c] =
              f2bf(acc[i][j][rr]);
    __syncthreads();
    bf16* dst = ((t == 0) ? qws : kws) + ((size_t)(b * Hq + h) * Sq + s0) * Dq;
#pragma unroll
    for (int p = 0; p < 4; ++p) {
      const int row = p * 32 + (tid >> 3);
      const int dlow = (tid & 7) * 8;
      const int s = s0 + row;
      bf16x8 lo = *(const bf16x8*)&Sm[row * 136 + dlow];
      bf16x8 hi = *(const bf16x8*)&Sm[row * 136 + 64 + dlow];
      bf16x8 olo, ohi;
#pragma unroll
      for (int e = 0; e < 8; ++e) {
        const int d = dlow + e;
        const float freq = __expf(-(float)d * 0.14391157f);
        const float ang = (float)s * freq;
        float sv, cv;
        __sincosf(ang, &sv, &cv);
        const float x1 = bf2f(lo[e]), x2 = bf2f(hi[e]);
        olo[e] = f2bf(x1 * cv - x2 * sv);
        ohi[e] = f2bf(x2 * cv + x1 * sv);
      }
      *(bf16x8*)&dst[(size_t)row * Dq + dlow] = olo;
      *(bf16x8*)&dst[(size_t)row * Dq + 64 + dlow] = ohi;
    }
  }
}

// ---------------------------------------------------------------------------
// Kernel 3: flash attention (R5 structure) + qt CU-pairing fix.
// Grid (16,16,2) = 512 blocks = exactly the resident-slot count; linear
// round-robin puts block id and id+256 (same x,y, b=0/1) on one CU. Flipping
// qt order for b=1 pairs qt with 15-qt on each CU -> uniform 34 chunks/CU
// (was 4..64, 2x tail on heaviest CUs).
// ---------------------------------------------------------------------------
__global__ __launch_bounds__(256, 2) void attn_kernel(
    const bf16* __restrict__ qws, const bf16* __restrict__ kws,
    const bf16* __restrict__ vtws, float* __restrict__ out) {
  __shared__ __align__(16) bf16 Kld[2][8192];
  __shared__ __align__(16) bf16 Vld[2][8192];
  __shared__ __align__(16) bf16 Plds[4][16][72];

  const int tid = threadIdx.x, lane = tid & 63, wave = tid >> 6;
  const int q4 = lane >> 4, c = lane & 15;
  const int h = blockIdx.y, b = blockIdx.z;
  const int qt = b ? blockIdx.x : (15 - blockIdx.x);  // CU-pair balance
  const size_t bh = (size_t)(b * Hq + h);
  const bf16* qbase = qws + bh * Sq * Dq;
  const bf16* kbase = kws + bh * Sq * Dq;
  const bf16* vbase = vtws + bh * Dq * Sq;
  const int q0 = qt * 128 + wave * 32;
  const float kSc = 0.08838834764831845f * 1.4426950408889634f;

  bf16x8 qf[2][4];
#pragma unroll
  for (int g = 0; g < 2; ++g)
#pragma unroll
    for (int ks = 0; ks < 4; ++ks)
      qf[g][ks] = *(const bf16x8*)
          &qbase[(size_t)(q0 + g * 16 + c) * Dq + ks * 32 + q4 * 8];

  f32x4 Ot[2][8];
  float m_i[2], l_i[2];
#pragma unroll
  for (int g = 0; g < 2; ++g) {
#pragma unroll
    for (int dj = 0; dj < 8; ++dj) Ot[g][dj] = {0.f, 0.f, 0.f, 0.f};
    m_i[g] = -1e30f; l_i[g] = 0.f;
  }

  const int nchunks = 2 * qt + 2;

#pragma unroll
  for (int it = 0; it < 4; ++it) {
    const int slot = it * 256 + tid;
    GLOAD_LDS16(kbase + (size_t)(slot & 63) * Dq + (slot >> 6) * 8,
                &Kld[0][slot * 8]);
    GLOAD_LDS16(vbase + (size_t)(slot & 127) * Sq + (slot >> 7) * 8,
                &Vld[0][slot * 8]);
  }
  __syncthreads();

  for (int kb = 0; kb < nchunks; ++kb) {
    const int buf = kb & 1;
    if (kb + 1 < nchunks) {
      const int nb = buf ^ 1;
      const int koff = (kb + 1) * 64;
#pragma unroll
      for (int it = 0; it < 4; ++it) {
        const int slot = it * 256 + tid;
        GLOAD_LDS16(kbase + (size_t)(koff + (slot & 63)) * Dq + (slot >> 6) * 8,
                    &Kld[nb][slot * 8]);
        GLOAD_LDS16(vbase + (size_t)(slot & 127) * Sq + koff + (slot >> 7) * 8,
                    &Vld[nb][slot * 8]);
      }
    }
    const bool masked = (kb >= 2 * qt);
#pragma unroll
    for (int g = 0; g < 2; ++g) {
      const int qg = q0 + g * 16 + c;
      f32x4 st[4];
#pragma unroll
      for (int j8 = 0; j8 < 4; ++j8) st[j8] = {0.f, 0.f, 0.f, 0.f};
#pragma unroll
      for (int ks = 0; ks < 4; ++ks) {
        const bf16x8 qv = qf[g][ks];
#pragma unroll
        for (int j8 = 0; j8 < 4; ++j8) {
          const bf16x8 kv = *(const bf16x8*)
              &Kld[buf][((ks * 4 + q4) * 64 + j8 * 16 + c) * 8];
          st[j8] = MFMA16(kv, qv, st[j8]);
        }
      }
      if (masked) {
        const int kb64 = kb * 64 + q4 * 4;
#pragma unroll
        for (int j8 = 0; j8 < 4; ++j8)
#pragma unroll
          for (int rr = 0; rr < 4; ++rr)
            if (kb64 + j8 * 16 + rr > qg) st[j8][rr] = -1e30f;
      }
      float mloc = -1e30f;
#pragma unroll
      for (int j8 = 0; j8 < 4; ++j8)
#pragma unroll
        for (int rr = 0; rr < 4; ++rr) mloc = fmaxf(mloc, st[j8][rr]);
      mloc = fmaxf(mloc, __shfl_xor(mloc, 16, 64));
      mloc = fmaxf(mloc, __shfl_xor(mloc, 32, 64));
      const float mn = fmaxf(m_i[g], mloc);
      const float alpha = exp2f((m_i[g] - mn) * kSc);
      m_i[g] = mn;
      float ssum = 0.f;
#pragma unroll
      for (int j8 = 0; j8 < 4; ++j8)
#pragma unroll
        for (int rr = 0; rr < 4; ++rr) {
          const float p = exp2f((st[j8][rr] - mn) * kSc);
          st[j8][rr] = p;
          ssum += p;
        }
      ssum += __shfl_xor(ssum, 16, 64);
      ssum += __shfl_xor(ssum, 32, 64);
      l_i[g] = l_i[g] * alpha + ssum;
#pragma unroll
      for (int dj = 0; dj < 8; ++dj) Ot[g][dj] *= alpha;
#pragma unroll
      for (int j8 = 0; j8 < 4; ++j8) {
        bf16x4 pk;
        pk[0] = f2bf(st[j8][0]); pk[1] = f2bf(st[j8][1]);
        pk[2] = f2bf(st[j8][2]); pk[3] = f2bf(st[j8][3]);
        *(bf16x4*)&Plds[wave][c][j8 * 16 + q4 * 4] = pk;
      }
#pragma unroll
      for (int ks = 0; ks < 2; ++ks) {
        const bf16x8 pv = *(const bf16x8*)&Plds[wave][c][ks * 32 + q4 * 8];
#pragma unroll
        for (int dj = 0; dj < 8; ++dj) {
          const bf16x8 vv = *(const bf16x8*)
              &Vld[buf][((ks * 4 + q4) * 128 + dj * 16 + c) * 8];
          Ot[g][dj] = MFMA16(vv, pv, Ot[g][dj]);
        }
      }
    }
    __syncthreads();
  }

#pragma unroll
  for (int g = 0; g < 2; ++g) {
    const float inv = 1.0f / l_i[g];
    float* orow = out + ((size_t)b * Sq + q0 + g * 16 + c) * Eq + h * Dq;
#pragma unroll
    for (int dj = 0; dj < 8; ++dj) {
      float4 o;
      o.x = Ot[g][dj][0] * inv; o.y = Ot[g][dj][1] * inv;
      o.z = Ot[g][dj][2] * inv; o.w = Ot[g][dj][3] * inv;
      *(float4*)&orow[dj * 16 + q4 * 4] = o;
    }
  }
}

// ---------------------------------------------------------------------------
extern "C" void kernel_launch(void* const* d_in, const int* in_sizes, int n_in,
                              void* d_out, int out_size, void* d_ws,
                              size_t ws_size, hipStream_t stream) {
  const float* x = (const float*)d_in[0];
  // d_in[1] = mask (causal tril) — implemented analytically, not read.
  const float* w = (const float*)d_in[2];
  float* out = (float*)d_out;

  const size_t nX = (size_t)Bq * Sq * Eq;         // 8,388,608
  const size_t nW = (size_t)Eq * N3E;             // 12,582,912
  const size_t perT = (size_t)Bq * Hq * Sq * Dq;  // 8,388,608

  bf16* xb = (bf16*)d_ws;
  bf16* wt = xb + nX;
  bf16* qws = wt + nW;
  bf16* kws = qws + perT;
  bf16* vtws = kws + perT;

  convert_x<<<nX / (256 * 8), 256, 0, stream>>>(x, xb);
  convert_wt<<<(Eq / 64) * (N3E / 64), 256, 0, stream>>>(w, wt);

  dim3 g1(N3E / 128, (Bq * Sq) / 128);  // 48 x 32
  gemm_qkv<<<g1, 256, 0, stream>>>(xb, wt, qws, kws, vtws);

  dim3 g3(Sq / 128, Hq, Bq);  // 16 x 16 x 2, qt CU-paired
  attn_kernel<<<g3, 256, 0, stream>>>(qws, kws, vtws, out);
}